// Round 30
// baseline (104.046 us; speedup 1.0000x reference)
//
#include <hip/hip_runtime.h>
#include <hip/hip_bf16.h>

// B=2, S=2048, E=1024, H=16, D=64. f32 in/out; bf16 MFMA internally.
// R29 = R28 (best, 103.67us) + GEMM1: drop sched_barrier(0) scheduler pin
//       (lgkmcnt+barriers retained; rule-#18 hazard not applicable here since
//       no MFMA consumes data guarded by that wait afterwards).
//   prep: fused x-cvt + weight transposes
//   GEMM1: 128x128 BK=32 depth-2 counted-vmcnt pipeline, 512 thr
//   attn: 4-wave 64-row heavy-first flash attn, no setprio (R28 win, -2.5us)
//   GEMM2: single-buffered BK=64 split arrays, 512 thr, BN=64

typedef __bf16 bf16;
typedef __bf16 bf16x4 __attribute__((ext_vector_type(4)));
typedef __bf16 bf16x8 __attribute__((ext_vector_type(8)));
typedef float  f32x4  __attribute__((ext_vector_type(4)));

#define MNEG (-1.0e30f)
#define QSCALE 0.1803368801f   // 0.125 * log2(e): folded into Q at GEMM1 epilogue

__device__ __forceinline__ void gload16(const bf16* g, bf16* l) {
  __builtin_amdgcn_global_load_lds((const __attribute__((address_space(1))) void*)g,
                                   (__attribute__((address_space(3))) void*)l, 16, 0, 0);
}

// ---------------- fused prep: x cvt (blocks 0..2047), W_attn^T, W_proj^T ----------------
__global__ __launch_bounds__(256) void prep_k(const float* __restrict__ x, bf16* __restrict__ xb,
                                              const float* __restrict__ Wa, bf16* __restrict__ WaT,
                                              const float* __restrict__ Wp, bf16* __restrict__ WpT) {
  const int bid = blockIdx.x;
  if (bid < 2048) {
    const int i = bid * 256 + threadIdx.x;
    f32x4 a = ((const f32x4*)x)[2 * i], b = ((const f32x4*)x)[2 * i + 1];
    bf16x8 o;
    for (int j = 0; j < 4; ++j) { o[j] = (bf16)a[j]; o[4 + j] = (bf16)b[j]; }
    ((bf16x8*)xb)[i] = o;
    return;
  }
  __shared__ bf16 t[64][68];
  const float* in; bf16* out; int C, cx, cy;
  if (bid < 2816) { in = Wa; out = WaT; C = 3072; const int tt = bid - 2048; cx = tt % 48; cy = tt / 48; }
  else            { in = Wp; out = WpT; C = 1024; const int tt = bid - 2816; cx = tt % 16; cy = tt / 16; }
  const int R = 1024;
  const int c0 = cx * 64, r0 = cy * 64;
  const int lr = threadIdx.x >> 4;
  const int lc = (threadIdx.x & 15) * 4;
  for (int i = 0; i < 4; ++i) {
    int r = lr + i * 16;
    f32x4 v = *(const f32x4*)(in + (size_t)(r0 + r) * C + c0 + lc);
    bf16x4 b;
    for (int j = 0; j < 4; ++j) b[j] = (bf16)v[j];
    *(bf16x4*)&t[r][lc] = b;
  }
  __syncthreads();
  for (int i = 0; i < 4; ++i) {
    int c = lr + i * 16;
    bf16x4 v;
    for (int j = 0; j < 4; ++j) v[j] = t[lc + j][c];
    *(bf16x4*)(out + (size_t)(c0 + c) * R + r0 + lc) = v;
  }
}

// ---------------- GEMM1: 128x128, BK=32, depth-2 counted-vmcnt pipeline, 512 thr ----------------
__global__ __launch_bounds__(512) void gemm_qkv(const bf16* __restrict__ A,
                                                const bf16* __restrict__ Bt,
                                                const float* __restrict__ bias,
                                                bf16* __restrict__ Qo,
                                                bf16* __restrict__ Ko,
                                                bf16* __restrict__ Vo,
                                                int M, int N, int K) {
  __shared__ bf16 As[3][128 * 32];
  __shared__ bf16 Bs[3][128 * 32];
  const int tid = threadIdx.x;
  const int w = tid >> 6, l = tid & 63;
  const int nx = gridDim.x;
  const int nwg = nx * gridDim.y;
  const int flat = blockIdx.y * nx + blockIdx.x;
  const int swz = (flat & 7) * (nwg >> 3) + (flat >> 3);
  const int m0 = (swz / nx) * 128, n0 = (swz % nx) * 128;
  const int wm = w >> 2, wn = w & 3;
  const int fr = l & 15, fg = l >> 4;
  const int grow = tid >> 2;
  const int gcol = (tid & 3) * 8;

  f32x4 acc[4][2] = {};

  auto stage = [&](int k0, int buf) {
    gload16(A  + (size_t)(m0 + grow) * K + k0 + gcol, As[buf] + 512 * w);
    gload16(Bt + (size_t)(n0 + grow) * K + k0 + gcol, Bs[buf] + 512 * w);
  };

  const int T = K / 32;
  stage(0, 0);
  stage(32, 1);

  int cur = 0;
  for (int i = 0; i < T; ++i) {
    const int k0 = i * 32;
    const int ahead = T - 1 - i;
    if (ahead >= 2) stage(k0 + 64, (cur + 2) % 3);

    if (ahead >= 2)      asm volatile("s_waitcnt vmcnt(4)" ::: "memory");
    else if (ahead == 1) asm volatile("s_waitcnt vmcnt(2)" ::: "memory");
    else                 asm volatile("s_waitcnt vmcnt(0)" ::: "memory");
    __builtin_amdgcn_s_barrier();
    asm volatile("" ::: "memory");

    const bf16* as = As[cur];
    const bf16* bs = Bs[cur];
    bf16x8 af[4], bfv[2];
    for (int mt = 0; mt < 4; ++mt)
      af[mt] = *(const bf16x8*)(as + (wm * 64 + mt * 16 + fr) * 32 + 8 * fg);
    for (int nt = 0; nt < 2; ++nt)
      bfv[nt] = *(const bf16x8*)(bs + (wn * 32 + nt * 16 + fr) * 32 + 8 * fg);
    for (int mt = 0; mt < 4; ++mt)
      for (int nt = 0; nt < 2; ++nt)
        acc[mt][nt] = __builtin_amdgcn_mfma_f32_16x16x32_bf16(af[mt], bfv[nt], acc[mt][nt], 0, 0, 0);

    asm volatile("s_waitcnt lgkmcnt(0)" ::: "memory");   // my ds_reads retired
    __builtin_amdgcn_s_barrier();                        // all waves done reading buf[cur]
    cur = (cur + 1) % 3;
  }

  for (int mt = 0; mt < 4; ++mt) {
    for (int nt = 0; nt < 2; ++nt) {
      const int row0 = m0 + wm * 64 + mt * 16 + 4 * fg;
      const int col = n0 + wn * 32 + nt * 16 + fr;
      const float bv = bias[col];
      const int which = col >> 10, h = (col >> 6) & 15, d = col & 63;
      const int b = row0 >> 11, s = row0 & 2047;
      if (which == 2) {
        bf16x4 vv;
        for (int r = 0; r < 4; ++r) vv[r] = (bf16)(acc[mt][nt][r] + bv);
        *(bf16x4*)(Vo + ((size_t)(b * 16 + h) * 64 + d) * 2048 + s) = vv;
      } else if (which == 0) {
        for (int r = 0; r < 4; ++r)
          Qo[((size_t)(b * 16 + h) * 2048 + s + r) * 64 + d] =
              (bf16)((acc[mt][nt][r] + bv) * QSCALE);
      } else {
        for (int r = 0; r < 4; ++r)
          Ko[((size_t)(b * 16 + h) * 2048 + s + r) * 64 + d] = (bf16)(acc[mt][nt][r] + bv);
      }
    }
  }
}

// ---------------- GEMM2: single-buffered BK=64 split arrays, 512 thr, BN=64 ----------------
__global__ __launch_bounds__(512) void gemm_proj(const bf16* __restrict__ A,
                                                 const bf16* __restrict__ Bt,
                                                 const float* __restrict__ bias,
                                                 float* __restrict__ C,
                                                 int M, int N, int K) {
  constexpr int BN = 64, WN = 2, MR = 32, MT = 2;
  __shared__ bf16 As0[128 * 32], As1[128 * 32];
  __shared__ bf16 Bs0[BN * 32],  Bs1[BN * 32];
  const int tid = threadIdx.x;
  const int w = tid >> 6, l = tid & 63;
  const int nx = gridDim.x;
  const int nwg = nx * gridDim.y;
  const int flat = blockIdx.y * nx + blockIdx.x;
  const int swz = (flat & 7) * (nwg >> 3) + (flat >> 3);
  const int m0 = (swz / nx) * 128, n0 = (swz % nx) * BN;
  const int wm = w / WN, wn = w % WN;
  const int fr = l & 15, fg = l >> 4;
  const int grow = tid >> 2;
  const int gcol = (tid & 3) * 8;

  f32x4 acc[MT][2] = {};

  for (int k0 = 0; k0 < K; k0 += 64) {
    __syncthreads();
    gload16(A + (size_t)(m0 + grow) * K + k0 + gcol,      As0 + 512 * w);
    gload16(A + (size_t)(m0 + grow) * K + k0 + 32 + gcol, As1 + 512 * w);
    if (w < 4) {
      gload16(Bt + (size_t)(n0 + grow) * K + k0 + gcol,      Bs0 + 512 * w);
      gload16(Bt + (size_t)(n0 + grow) * K + k0 + 32 + gcol, Bs1 + 512 * w);
    }
    __syncthreads();

    bf16x8 af[MT][2], bfv[2][2];
    for (int mt = 0; mt < MT; ++mt) {
      af[mt][0] = *(const bf16x8*)(As0 + (wm * MR + mt * 16 + fr) * 32 + 8 * fg);
      af[mt][1] = *(const bf16x8*)(As1 + (wm * MR + mt * 16 + fr) * 32 + 8 * fg);
    }
    for (int nt = 0; nt < 2; ++nt) {
      bfv[nt][0] = *(const bf16x8*)(Bs0 + (wn * 32 + nt * 16 + fr) * 32 + 8 * fg);
      bfv[nt][1] = *(const bf16x8*)(Bs1 + (wn * 32 + nt * 16 + fr) * 32 + 8 * fg);
    }
    for (int mt = 0; mt < MT; ++mt)
      for (int nt = 0; nt < 2; ++nt) {
        acc[mt][nt] = __builtin_amdgcn_mfma_f32_16x16x32_bf16(af[mt][0], bfv[nt][0], acc[mt][nt], 0, 0, 0);
        acc[mt][nt] = __builtin_amdgcn_mfma_f32_16x16x32_bf16(af[mt][1], bfv[nt][1], acc[mt][nt], 0, 0, 0);
      }
  }

  for (int mt = 0; mt < MT; ++mt)
    for (int nt = 0; nt < 2; ++nt) {
      const int row0 = m0 + wm * MR + mt * 16 + 4 * fg;
      const int col = n0 + wn * 32 + nt * 16 + fr;
      const float bv = bias[col];
      for (int r = 0; r < 4; ++r)
        C[(size_t)(row0 + r) * N + col] = acc[mt][nt][r] + bv;
    }
}

// ---------------- flash attention: 4-wave 64-row q-tile/block, heavy-first, NO setprio ----------------
__global__ __launch_bounds__(256, 3) void attn_k(const bf16* __restrict__ Qw,
                                                 const bf16* __restrict__ Kw,
                                                 const bf16* __restrict__ VtG,
                                                 bf16* __restrict__ AO) {
  __shared__ bf16 Ks[128 * 72];        // 18432 B
  __shared__ bf16 Vt[64 * 136];        // 17408 B
  __shared__ bf16 Ps[4 * 16 * 72];     //  9216 B
  const int tid = threadIdx.x, w = tid >> 6, l = tid & 63;
  const int bid = blockIdx.x;
  const int bh = ((bid & 7) << 2) | ((bid >> 3) & 3);
  const int qt = 31 - (bid >> 5);             // heavy-first
  const int q0 = qt * 64;
  const int fr = l & 15, fg = l >> 4;
  const size_t base = (size_t)bh * 2048 * 64;
  const int qw0 = q0 + w * 16;
  const int q = qw0 + fr;
  bf16* Pw = Ps + w * 16 * 72;
  const int r8 = tid >> 3, c8 = (tid & 7) * 8;
  const int r16 = tid >> 4, c16 = (tid & 15) * 8;

  bf16x8 qf[2];
  for (int t = 0; t < 2; ++t)
    qf[t] = *(const bf16x8*)(Qw + base + (size_t)(qw0 + fr) * 64 + 32 * t + 8 * fg);

  f32x4 oacc[4] = {};
  float lsum = 0.f;
  bf16x8 kreg[4], vreg[4];

  auto load_tile = [&](int kt) {
    for (int c = 0; c < 4; ++c) {
      kreg[c] = *(const bf16x8*)(Kw + base + (size_t)(kt + r8 + 32 * c) * 64 + c8);
      vreg[c] = *(const bf16x8*)(VtG + base + (size_t)(r16 + 16 * c) * 2048 + kt + c16);
    }
  };
  auto write_tile = [&]() {
    for (int c = 0; c < 4; ++c) {
      *(bf16x8*)(Ks + (r8 + 32 * c) * 72 + c8) = kreg[c];
      *(bf16x8*)(Vt + (r16 + 16 * c) * 136 + c16) = vreg[c];
    }
  };

  load_tile(0);
  write_tile();
  __syncthreads();

  for (int kt = 0; kt <= q0; kt += 128) {
    const bool havenext = (kt + 128 <= q0);
    if (havenext) load_tile(kt + 128);      // T14: issue early

    for (int h = 0; h < 2; ++h) {
      const int kh = kt + 64 * h;
      if (kh > q0) break;

      f32x4 sc[4];
      for (int c = 0; c < 4; ++c) {
        bf16x8 kf0 = *(const bf16x8*)(Ks + (64 * h + c * 16 + fr) * 72 + 8 * fg);
        bf16x8 kf1 = *(const bf16x8*)(Ks + (64 * h + c * 16 + fr) * 72 + 32 + 8 * fg);
        f32x4 z = {};
        z = __builtin_amdgcn_mfma_f32_16x16x32_bf16(kf0, qf[0], z, 0, 0, 0);
        sc[c] = __builtin_amdgcn_mfma_f32_16x16x32_bf16(kf1, qf[1], z, 0, 0, 0);
      }

      const bool need_mask = (kh + 63 > qw0);
      float psum = 0.f;
      for (int c = 0; c < 4; ++c) {
        bf16x4 pb;
        for (int r = 0; r < 4; ++r) {
          float s = sc[c][r];
          if (need_mask && (kh + c * 16 + 4 * fg + r > q)) s = MNEG;
          const float pv = __builtin_amdgcn_exp2f(s);
          psum += pv;
          pb[r] = (bf16)pv;
        }
        *(bf16x4*)(Pw + fr * 72 + c * 16 + 4 * fg) = pb;
      }
      psum += __shfl_xor(psum, 16, 64);
      psum += __shfl_xor(psum, 32, 64);
      lsum += psum;

      asm volatile("" ::: "memory");   // P writes before P reads (in-wave DS order)
      for (int t = 0; t < 2; ++t) {
        bf16x8 pa = *(const bf16x8*)(Pw + fr * 72 + 32 * t + 8 * fg);
        for (int dt = 0; dt < 4; ++dt) {
          bf16x8 vf = *(const bf16x8*)(Vt + (dt * 16 + fr) * 136 + 64 * h + 32 * t + 8 * fg);
          oacc[dt] = __builtin_amdgcn_mfma_f32_16x16x32_bf16(pa, vf, oacc[dt], 0, 0, 0);
        }
      }
      asm volatile("" ::: "memory");   // Pw reused next half
    }

    if (!havenext) break;
    __syncthreads();
    write_tile();                           // T14: write-late
    __syncthreads();
  }

  const int b = bh >> 4, h = bh & 15;
  float linv[4];
  for (int r = 0; r < 4; ++r)
    linv[r] = 1.f / __shfl(lsum, (l & 48) | (4 * fg + r), 64);
  for (int dt = 0; dt < 4; ++dt)
    for (int r = 0; r < 4; ++r) {
      const int qq = qw0 + 4 * fg + r;
      AO[(size_t)(b * 2048 + qq) * 1024 + h * 64 + dt * 16 + fr] =
          (bf16)(oacc[dt][r] * linv[r]);
    }
}

// ---------------- launch ----------------
extern "C" void kernel_launch(void* const* d_in, const int* in_sizes, int n_in,
                              void* d_out, int out_size, void* d_ws, size_t ws_size,
                              hipStream_t stream) {
  const float* x      = (const float*)d_in[0];
  const float* W_attn = (const float*)d_in[1];
  const float* b_attn = (const float*)d_in[2];
  const float* W_proj = (const float*)d_in[3];
  const float* b_proj = (const float*)d_in[4];
  float* out = (float*)d_out;

  char* ws = (char*)d_ws;
  bf16* WaT = (bf16*)(ws);                 // 6291456 B
  bf16* WpT = (bf16*)(ws + 6291456);       // 2097152 B
  bf16* Qw  = (bf16*)(ws + 8388608);       // [B,H,S,D] (pre-scaled by QSCALE)
  bf16* Kw  = (bf16*)(ws + 16777216);      // [B,H,S,D]
  bf16* VtG = (bf16*)(ws + 25165824);      // [B,H,D,S]
  bf16* AO  = (bf16*)(ws + 33554432);      // [B,S,E] bf16; aliased as xb pre-attn
  bf16* xb  = AO;

  prep_k<<<3072, 256, 0, stream>>>(x, xb, W_attn, WaT, W_proj, WpT);

  gemm_qkv<<<dim3(24, 32), 512, 0, stream>>>(
      xb, WaT, b_attn, Qw, Kw, VtG, 4096, 3072, 1024);

  attn_k<<<1024, 256, 0, stream>>>(Qw, Kw, VtG, AO);

  gemm_proj<<<dim3(16, 32), 512, 0, stream>>>(
      AO, WpT, b_proj, out, 4096, 1024, 1024);
}

// Round 31
// 103.818 us; speedup vs baseline: 1.0022x; 1.0022x over previous
//
#include <hip/hip_runtime.h>
#include <hip/hip_bf16.h>

// B=2, S=2048, E=1024, H=16, D=64. f32 in/out; bf16 MFMA internally.
// FINAL (session best: 103.7-104.0us; baseline-correct was 274.9us -> 2.65x):
//   prep: fused x-cvt + weight transposes (BW-bound, ~8us)
//   GEMM1: 128x128 BK=32 depth-2 counted-vmcnt pipeline, 512 thr (~31us, ~810 TF)
//   attn: 4-wave 64-row heavy-first flash attn, swapped QK^T (lane-local softmax),
//         no-max exp2 softmax, bh->XCD swizzle, T14 prefetch, NO setprio (~47.5us)
//   GEMM2: single-buffered BK=64 split arrays, 512 thr, BN=64 (~10us)

typedef __bf16 bf16;
typedef __bf16 bf16x4 __attribute__((ext_vector_type(4)));
typedef __bf16 bf16x8 __attribute__((ext_vector_type(8)));
typedef float  f32x4  __attribute__((ext_vector_type(4)));

#define MNEG (-1.0e30f)
#define QSCALE 0.1803368801f   // 0.125 * log2(e): folded into Q at GEMM1 epilogue

__device__ __forceinline__ void gload16(const bf16* g, bf16* l) {
  __builtin_amdgcn_global_load_lds((const __attribute__((address_space(1))) void*)g,
                                   (__attribute__((address_space(3))) void*)l, 16, 0, 0);
}

// ---------------- fused prep: x cvt (blocks 0..2047), W_attn^T, W_proj^T ----------------
__global__ __launch_bounds__(256) void prep_k(const float* __restrict__ x, bf16* __restrict__ xb,
                                              const float* __restrict__ Wa, bf16* __restrict__ WaT,
                                              const float* __restrict__ Wp, bf16* __restrict__ WpT) {
  const int bid = blockIdx.x;
  if (bid < 2048) {
    const int i = bid * 256 + threadIdx.x;
    f32x4 a = ((const f32x4*)x)[2 * i], b = ((const f32x4*)x)[2 * i + 1];
    bf16x8 o;
    for (int j = 0; j < 4; ++j) { o[j] = (bf16)a[j]; o[4 + j] = (bf16)b[j]; }
    ((bf16x8*)xb)[i] = o;
    return;
  }
  __shared__ bf16 t[64][68];
  const float* in; bf16* out; int C, cx, cy;
  if (bid < 2816) { in = Wa; out = WaT; C = 3072; const int tt = bid - 2048; cx = tt % 48; cy = tt / 48; }
  else            { in = Wp; out = WpT; C = 1024; const int tt = bid - 2816; cx = tt % 16; cy = tt / 16; }
  const int R = 1024;
  const int c0 = cx * 64, r0 = cy * 64;
  const int lr = threadIdx.x >> 4;
  const int lc = (threadIdx.x & 15) * 4;
  for (int i = 0; i < 4; ++i) {
    int r = lr + i * 16;
    f32x4 v = *(const f32x4*)(in + (size_t)(r0 + r) * C + c0 + lc);
    bf16x4 b;
    for (int j = 0; j < 4; ++j) b[j] = (bf16)v[j];
    *(bf16x4*)&t[r][lc] = b;
  }
  __syncthreads();
  for (int i = 0; i < 4; ++i) {
    int c = lr + i * 16;
    bf16x4 v;
    for (int j = 0; j < 4; ++j) v[j] = t[lc + j][c];
    *(bf16x4*)(out + (size_t)(c0 + c) * R + r0 + lc) = v;
  }
}

// ---------------- GEMM1: 128x128, BK=32, depth-2 counted-vmcnt pipeline, 512 thr ----------------
__global__ __launch_bounds__(512) void gemm_qkv(const bf16* __restrict__ A,
                                                const bf16* __restrict__ Bt,
                                                const float* __restrict__ bias,
                                                bf16* __restrict__ Qo,
                                                bf16* __restrict__ Ko,
                                                bf16* __restrict__ Vo,
                                                int M, int N, int K) {
  __shared__ bf16 As[3][128 * 32];
  __shared__ bf16 Bs[3][128 * 32];
  const int tid = threadIdx.x;
  const int w = tid >> 6, l = tid & 63;
  const int nx = gridDim.x;
  const int nwg = nx * gridDim.y;
  const int flat = blockIdx.y * nx + blockIdx.x;
  const int swz = (flat & 7) * (nwg >> 3) + (flat >> 3);
  const int m0 = (swz / nx) * 128, n0 = (swz % nx) * 128;
  const int wm = w >> 2, wn = w & 3;
  const int fr = l & 15, fg = l >> 4;
  const int grow = tid >> 2;
  const int gcol = (tid & 3) * 8;

  f32x4 acc[4][2] = {};

  auto stage = [&](int k0, int buf) {
    gload16(A  + (size_t)(m0 + grow) * K + k0 + gcol, As[buf] + 512 * w);
    gload16(Bt + (size_t)(n0 + grow) * K + k0 + gcol, Bs[buf] + 512 * w);
  };

  const int T = K / 32;
  stage(0, 0);
  stage(32, 1);

  int cur = 0;
  for (int i = 0; i < T; ++i) {
    const int k0 = i * 32;
    const int ahead = T - 1 - i;
    if (ahead >= 2) stage(k0 + 64, (cur + 2) % 3);

    if (ahead >= 2)      asm volatile("s_waitcnt vmcnt(4)" ::: "memory");
    else if (ahead == 1) asm volatile("s_waitcnt vmcnt(2)" ::: "memory");
    else                 asm volatile("s_waitcnt vmcnt(0)" ::: "memory");
    __builtin_amdgcn_s_barrier();
    asm volatile("" ::: "memory");

    const bf16* as = As[cur];
    const bf16* bs = Bs[cur];
    bf16x8 af[4], bfv[2];
    for (int mt = 0; mt < 4; ++mt)
      af[mt] = *(const bf16x8*)(as + (wm * 64 + mt * 16 + fr) * 32 + 8 * fg);
    for (int nt = 0; nt < 2; ++nt)
      bfv[nt] = *(const bf16x8*)(bs + (wn * 32 + nt * 16 + fr) * 32 + 8 * fg);
    for (int mt = 0; mt < 4; ++mt)
      for (int nt = 0; nt < 2; ++nt)
        acc[mt][nt] = __builtin_amdgcn_mfma_f32_16x16x32_bf16(af[mt], bfv[nt], acc[mt][nt], 0, 0, 0);

    asm volatile("s_waitcnt lgkmcnt(0)" ::: "memory");   // my ds_reads retired
    __builtin_amdgcn_s_barrier();                        // all waves done reading buf[cur]
    cur = (cur + 1) % 3;
  }

  for (int mt = 0; mt < 4; ++mt) {
    for (int nt = 0; nt < 2; ++nt) {
      const int row0 = m0 + wm * 64 + mt * 16 + 4 * fg;
      const int col = n0 + wn * 32 + nt * 16 + fr;
      const float bv = bias[col];
      const int which = col >> 10, h = (col >> 6) & 15, d = col & 63;
      const int b = row0 >> 11, s = row0 & 2047;
      if (which == 2) {
        bf16x4 vv;
        for (int r = 0; r < 4; ++r) vv[r] = (bf16)(acc[mt][nt][r] + bv);
        *(bf16x4*)(Vo + ((size_t)(b * 16 + h) * 64 + d) * 2048 + s) = vv;
      } else if (which == 0) {
        for (int r = 0; r < 4; ++r)
          Qo[((size_t)(b * 16 + h) * 2048 + s + r) * 64 + d] =
              (bf16)((acc[mt][nt][r] + bv) * QSCALE);
      } else {
        for (int r = 0; r < 4; ++r)
          Ko[((size_t)(b * 16 + h) * 2048 + s + r) * 64 + d] = (bf16)(acc[mt][nt][r] + bv);
      }
    }
  }
}

// ---------------- GEMM2: single-buffered BK=64 split arrays, 512 thr, BN=64 ----------------
__global__ __launch_bounds__(512) void gemm_proj(const bf16* __restrict__ A,
                                                 const bf16* __restrict__ Bt,
                                                 const float* __restrict__ bias,
                                                 float* __restrict__ C,
                                                 int M, int N, int K) {
  constexpr int BN = 64, WN = 2, MR = 32, MT = 2;
  __shared__ bf16 As0[128 * 32], As1[128 * 32];
  __shared__ bf16 Bs0[BN * 32],  Bs1[BN * 32];
  const int tid = threadIdx.x;
  const int w = tid >> 6, l = tid & 63;
  const int nx = gridDim.x;
  const int nwg = nx * gridDim.y;
  const int flat = blockIdx.y * nx + blockIdx.x;
  const int swz = (flat & 7) * (nwg >> 3) + (flat >> 3);
  const int m0 = (swz / nx) * 128, n0 = (swz % nx) * BN;
  const int wm = w / WN, wn = w % WN;
  const int fr = l & 15, fg = l >> 4;
  const int grow = tid >> 2;
  const int gcol = (tid & 3) * 8;

  f32x4 acc[MT][2] = {};

  for (int k0 = 0; k0 < K; k0 += 64) {
    __syncthreads();
    gload16(A + (size_t)(m0 + grow) * K + k0 + gcol,      As0 + 512 * w);
    gload16(A + (size_t)(m0 + grow) * K + k0 + 32 + gcol, As1 + 512 * w);
    if (w < 4) {
      gload16(Bt + (size_t)(n0 + grow) * K + k0 + gcol,      Bs0 + 512 * w);
      gload16(Bt + (size_t)(n0 + grow) * K + k0 + 32 + gcol, Bs1 + 512 * w);
    }
    __syncthreads();

    bf16x8 af[MT][2], bfv[2][2];
    for (int mt = 0; mt < MT; ++mt) {
      af[mt][0] = *(const bf16x8*)(As0 + (wm * MR + mt * 16 + fr) * 32 + 8 * fg);
      af[mt][1] = *(const bf16x8*)(As1 + (wm * MR + mt * 16 + fr) * 32 + 8 * fg);
    }
    for (int nt = 0; nt < 2; ++nt) {
      bfv[nt][0] = *(const bf16x8*)(Bs0 + (wn * 32 + nt * 16 + fr) * 32 + 8 * fg);
      bfv[nt][1] = *(const bf16x8*)(Bs1 + (wn * 32 + nt * 16 + fr) * 32 + 8 * fg);
    }
    for (int mt = 0; mt < MT; ++mt)
      for (int nt = 0; nt < 2; ++nt) {
        acc[mt][nt] = __builtin_amdgcn_mfma_f32_16x16x32_bf16(af[mt][0], bfv[nt][0], acc[mt][nt], 0, 0, 0);
        acc[mt][nt] = __builtin_amdgcn_mfma_f32_16x16x32_bf16(af[mt][1], bfv[nt][1], acc[mt][nt], 0, 0, 0);
      }
  }

  for (int mt = 0; mt < MT; ++mt)
    for (int nt = 0; nt < 2; ++nt) {
      const int row0 = m0 + wm * MR + mt * 16 + 4 * fg;
      const int col = n0 + wn * 32 + nt * 16 + fr;
      const float bv = bias[col];
      for (int r = 0; r < 4; ++r)
        C[(size_t)(row0 + r) * N + col] = acc[mt][nt][r] + bv;
    }
}

// ---------------- flash attention: 4-wave 64-row q-tile/block, heavy-first, NO setprio ----------------
__global__ __launch_bounds__(256, 3) void attn_k(const bf16* __restrict__ Qw,
                                                 const bf16* __restrict__ Kw,
                                                 const bf16* __restrict__ VtG,
                                                 bf16* __restrict__ AO) {
  __shared__ bf16 Ks[128 * 72];        // 18432 B
  __shared__ bf16 Vt[64 * 136];        // 17408 B
  __shared__ bf16 Ps[4 * 16 * 72];     //  9216 B
  const int tid = threadIdx.x, w = tid >> 6, l = tid & 63;
  const int bid = blockIdx.x;
  const int bh = ((bid & 7) << 2) | ((bid >> 3) & 3);
  const int qt = 31 - (bid >> 5);             // heavy-first
  const int q0 = qt * 64;
  const int fr = l & 15, fg = l >> 4;
  const size_t base = (size_t)bh * 2048 * 64;
  const int qw0 = q0 + w * 16;
  const int q = qw0 + fr;
  bf16* Pw = Ps + w * 16 * 72;
  const int r8 = tid >> 3, c8 = (tid & 7) * 8;
  const int r16 = tid >> 4, c16 = (tid & 15) * 8;

  bf16x8 qf[2];
  for (int t = 0; t < 2; ++t)
    qf[t] = *(const bf16x8*)(Qw + base + (size_t)(qw0 + fr) * 64 + 32 * t + 8 * fg);

  f32x4 oacc[4] = {};
  float lsum = 0.f;
  bf16x8 kreg[4], vreg[4];

  auto load_tile = [&](int kt) {
    for (int c = 0; c < 4; ++c) {
      kreg[c] = *(const bf16x8*)(Kw + base + (size_t)(kt + r8 + 32 * c) * 64 + c8);
      vreg[c] = *(const bf16x8*)(VtG + base + (size_t)(r16 + 16 * c) * 2048 + kt + c16);
    }
  };
  auto write_tile = [&]() {
    for (int c = 0; c < 4; ++c) {
      *(bf16x8*)(Ks + (r8 + 32 * c) * 72 + c8) = kreg[c];
      *(bf16x8*)(Vt + (r16 + 16 * c) * 136 + c16) = vreg[c];
    }
  };

  load_tile(0);
  write_tile();
  __syncthreads();

  for (int kt = 0; kt <= q0; kt += 128) {
    const bool havenext = (kt + 128 <= q0);
    if (havenext) load_tile(kt + 128);      // T14: issue early

    for (int h = 0; h < 2; ++h) {
      const int kh = kt + 64 * h;
      if (kh > q0) break;

      f32x4 sc[4];
      for (int c = 0; c < 4; ++c) {
        bf16x8 kf0 = *(const bf16x8*)(Ks + (64 * h + c * 16 + fr) * 72 + 8 * fg);
        bf16x8 kf1 = *(const bf16x8*)(Ks + (64 * h + c * 16 + fr) * 72 + 32 + 8 * fg);
        f32x4 z = {};
        z = __builtin_amdgcn_mfma_f32_16x16x32_bf16(kf0, qf[0], z, 0, 0, 0);
        sc[c] = __builtin_amdgcn_mfma_f32_16x16x32_bf16(kf1, qf[1], z, 0, 0, 0);
      }

      const bool need_mask = (kh + 63 > qw0);
      float psum = 0.f;
      for (int c = 0; c < 4; ++c) {
        bf16x4 pb;
        for (int r = 0; r < 4; ++r) {
          float s = sc[c][r];
          if (need_mask && (kh + c * 16 + 4 * fg + r > q)) s = MNEG;
          const float pv = __builtin_amdgcn_exp2f(s);
          psum += pv;
          pb[r] = (bf16)pv;
        }
        *(bf16x4*)(Pw + fr * 72 + c * 16 + 4 * fg) = pb;
      }
      psum += __shfl_xor(psum, 16, 64);
      psum += __shfl_xor(psum, 32, 64);
      lsum += psum;

      asm volatile("" ::: "memory");   // P writes before P reads (in-wave DS order)
      for (int t = 0; t < 2; ++t) {
        bf16x8 pa = *(const bf16x8*)(Pw + fr * 72 + 32 * t + 8 * fg);
        for (int dt = 0; dt < 4; ++dt) {
          bf16x8 vf = *(const bf16x8*)(Vt + (dt * 16 + fr) * 136 + 64 * h + 32 * t + 8 * fg);
          oacc[dt] = __builtin_amdgcn_mfma_f32_16x16x32_bf16(pa, vf, oacc[dt], 0, 0, 0);
        }
      }
      asm volatile("" ::: "memory");   // Pw reused next half
    }

    if (!havenext) break;
    __syncthreads();
    write_tile();                           // T14: write-late
    __syncthreads();
  }

  const int b = bh >> 4, h = bh & 15;
  float linv[4];
  for (int r = 0; r < 4; ++r)
    linv[r] = 1.f / __shfl(lsum, (l & 48) | (4 * fg + r), 64);
  for (int dt = 0; dt < 4; ++dt)
    for (int r = 0; r < 4; ++r) {
      const int qq = qw0 + 4 * fg + r;
      AO[(size_t)(b * 2048 + qq) * 1024 + h * 64 + dt * 16 + fr] =
          (bf16)(oacc[dt][r] * linv[r]);
    }
}

// ---------------- launch ----------------
extern "C" void kernel_launch(void* const* d_in, const int* in_sizes, int n_in,
                              void* d_out, int out_size, void* d_ws, size_t ws_size,
                              hipStream_t stream) {
  const float* x      = (const float*)d_in[0];
  const float* W_attn = (const float*)d_in[1];
  const float* b_attn = (const float*)d_in[2];
  const float* W_proj = (const float*)d_in[3];
  const float* b_proj = (const float*)d_in[4];
  float* out = (float*)d_out;

  char* ws = (char*)d_ws;
  bf16* WaT = (bf16*)(ws);                 // 6291456 B
  bf16* WpT = (bf16*)(ws + 6291456);       // 2097152 B
  bf16* Qw  = (bf16*)(ws + 8388608);       // [B,H,S,D] (pre-scaled by QSCALE)
  bf16* Kw  = (bf16*)(ws + 16777216);      // [B,H,S,D]
  bf16* VtG = (bf16*)(ws + 25165824);      // [B,H,D,S]
  bf16* AO  = (bf16*)(ws + 33554432);      // [B,S,E] bf16; aliased as xb pre-attn
  bf16* xb  = AO;

  prep_k<<<3072, 256, 0, stream>>>(x, xb, W_attn, WaT, W_proj, WpT);

  gemm_qkv<<<dim3(24, 32), 512, 0, stream>>>(
      xb, WaT, b_attn, Qw, Kw, VtG, 4096, 3072, 1024);

  attn_k<<<1024, 256, 0, stream>>>(Qw, Kw, VtG, AO);

  gemm_proj<<<dim3(16, 32), 512, 0, stream>>>(
      AO, WpT, b_proj, out, 4096, 1024, 1024);
}

// Round 32
// 103.574 us; speedup vs baseline: 1.0046x; 1.0024x over previous
//
#include <hip/hip_runtime.h>
#include <hip/hip_bf16.h>

// B=2, S=2048, E=1024, H=16, D=64. f32 in/out; bf16 MFMA internally.
// FINAL (session best: 103.7-104.0us, reproduced 4x; baseline-correct was 274.9us -> 2.65x):
//   prep: fused x-cvt + weight transposes (~8us, at HBM BW roofline)
//   GEMM1: 128x128 BK=32 depth-2 counted-vmcnt pipeline, 512 thr (~31us, ~810 TF)
//   attn: 4-wave 64-row heavy-first flash attn, swapped QK^T (lane-local softmax),
//         no-max exp2 softmax, bh->XCD swizzle, T14 prefetch, NO setprio (~47.5us)
//   GEMM2: single-buffered BK=64 split arrays, 512 thr, BN=64 (~10us)

typedef __bf16 bf16;
typedef __bf16 bf16x4 __attribute__((ext_vector_type(4)));
typedef __bf16 bf16x8 __attribute__((ext_vector_type(8)));
typedef float  f32x4  __attribute__((ext_vector_type(4)));

#define MNEG (-1.0e30f)
#define QSCALE 0.1803368801f   // 0.125 * log2(e): folded into Q at GEMM1 epilogue

__device__ __forceinline__ void gload16(const bf16* g, bf16* l) {
  __builtin_amdgcn_global_load_lds((const __attribute__((address_space(1))) void*)g,
                                   (__attribute__((address_space(3))) void*)l, 16, 0, 0);
}

// ---------------- fused prep: x cvt (blocks 0..2047), W_attn^T, W_proj^T ----------------
__global__ __launch_bounds__(256) void prep_k(const float* __restrict__ x, bf16* __restrict__ xb,
                                              const float* __restrict__ Wa, bf16* __restrict__ WaT,
                                              const float* __restrict__ Wp, bf16* __restrict__ WpT) {
  const int bid = blockIdx.x;
  if (bid < 2048) {
    const int i = bid * 256 + threadIdx.x;
    f32x4 a = ((const f32x4*)x)[2 * i], b = ((const f32x4*)x)[2 * i + 1];
    bf16x8 o;
    for (int j = 0; j < 4; ++j) { o[j] = (bf16)a[j]; o[4 + j] = (bf16)b[j]; }
    ((bf16x8*)xb)[i] = o;
    return;
  }
  __shared__ bf16 t[64][68];
  const float* in; bf16* out; int C, cx, cy;
  if (bid < 2816) { in = Wa; out = WaT; C = 3072; const int tt = bid - 2048; cx = tt % 48; cy = tt / 48; }
  else            { in = Wp; out = WpT; C = 1024; const int tt = bid - 2816; cx = tt % 16; cy = tt / 16; }
  const int R = 1024;
  const int c0 = cx * 64, r0 = cy * 64;
  const int lr = threadIdx.x >> 4;
  const int lc = (threadIdx.x & 15) * 4;
  for (int i = 0; i < 4; ++i) {
    int r = lr + i * 16;
    f32x4 v = *(const f32x4*)(in + (size_t)(r0 + r) * C + c0 + lc);
    bf16x4 b;
    for (int j = 0; j < 4; ++j) b[j] = (bf16)v[j];
    *(bf16x4*)&t[r][lc] = b;
  }
  __syncthreads();
  for (int i = 0; i < 4; ++i) {
    int c = lr + i * 16;
    bf16x4 v;
    for (int j = 0; j < 4; ++j) v[j] = t[lc + j][c];
    *(bf16x4*)(out + (size_t)(c0 + c) * R + r0 + lc) = v;
  }
}

// ---------------- GEMM1: 128x128, BK=32, depth-2 counted-vmcnt pipeline, 512 thr ----------------
__global__ __launch_bounds__(512) void gemm_qkv(const bf16* __restrict__ A,
                                                const bf16* __restrict__ Bt,
                                                const float* __restrict__ bias,
                                                bf16* __restrict__ Qo,
                                                bf16* __restrict__ Ko,
                                                bf16* __restrict__ Vo,
                                                int M, int N, int K) {
  __shared__ bf16 As[3][128 * 32];
  __shared__ bf16 Bs[3][128 * 32];
  const int tid = threadIdx.x;
  const int w = tid >> 6, l = tid & 63;
  const int nx = gridDim.x;
  const int nwg = nx * gridDim.y;
  const int flat = blockIdx.y * nx + blockIdx.x;
  const int swz = (flat & 7) * (nwg >> 3) + (flat >> 3);
  const int m0 = (swz / nx) * 128, n0 = (swz % nx) * 128;
  const int wm = w >> 2, wn = w & 3;
  const int fr = l & 15, fg = l >> 4;
  const int grow = tid >> 2;
  const int gcol = (tid & 3) * 8;

  f32x4 acc[4][2] = {};

  auto stage = [&](int k0, int buf) {
    gload16(A  + (size_t)(m0 + grow) * K + k0 + gcol, As[buf] + 512 * w);
    gload16(Bt + (size_t)(n0 + grow) * K + k0 + gcol, Bs[buf] + 512 * w);
  };

  const int T = K / 32;
  stage(0, 0);
  stage(32, 1);

  int cur = 0;
  for (int i = 0; i < T; ++i) {
    const int k0 = i * 32;
    const int ahead = T - 1 - i;
    if (ahead >= 2) stage(k0 + 64, (cur + 2) % 3);

    if (ahead >= 2)      asm volatile("s_waitcnt vmcnt(4)" ::: "memory");
    else if (ahead == 1) asm volatile("s_waitcnt vmcnt(2)" ::: "memory");
    else                 asm volatile("s_waitcnt vmcnt(0)" ::: "memory");
    __builtin_amdgcn_s_barrier();
    asm volatile("" ::: "memory");

    const bf16* as = As[cur];
    const bf16* bs = Bs[cur];
    bf16x8 af[4], bfv[2];
    for (int mt = 0; mt < 4; ++mt)
      af[mt] = *(const bf16x8*)(as + (wm * 64 + mt * 16 + fr) * 32 + 8 * fg);
    for (int nt = 0; nt < 2; ++nt)
      bfv[nt] = *(const bf16x8*)(bs + (wn * 32 + nt * 16 + fr) * 32 + 8 * fg);
    for (int mt = 0; mt < 4; ++mt)
      for (int nt = 0; nt < 2; ++nt)
        acc[mt][nt] = __builtin_amdgcn_mfma_f32_16x16x32_bf16(af[mt], bfv[nt], acc[mt][nt], 0, 0, 0);

    asm volatile("s_waitcnt lgkmcnt(0)" ::: "memory");   // my ds_reads retired
    __builtin_amdgcn_s_barrier();                        // all waves done reading buf[cur]
    cur = (cur + 1) % 3;
  }

  for (int mt = 0; mt < 4; ++mt) {
    for (int nt = 0; nt < 2; ++nt) {
      const int row0 = m0 + wm * 64 + mt * 16 + 4 * fg;
      const int col = n0 + wn * 32 + nt * 16 + fr;
      const float bv = bias[col];
      const int which = col >> 10, h = (col >> 6) & 15, d = col & 63;
      const int b = row0 >> 11, s = row0 & 2047;
      if (which == 2) {
        bf16x4 vv;
        for (int r = 0; r < 4; ++r) vv[r] = (bf16)(acc[mt][nt][r] + bv);
        *(bf16x4*)(Vo + ((size_t)(b * 16 + h) * 64 + d) * 2048 + s) = vv;
      } else if (which == 0) {
        for (int r = 0; r < 4; ++r)
          Qo[((size_t)(b * 16 + h) * 2048 + s + r) * 64 + d] =
              (bf16)((acc[mt][nt][r] + bv) * QSCALE);
      } else {
        for (int r = 0; r < 4; ++r)
          Ko[((size_t)(b * 16 + h) * 2048 + s + r) * 64 + d] = (bf16)(acc[mt][nt][r] + bv);
      }
    }
  }
}

// ---------------- GEMM2: single-buffered BK=64 split arrays, 512 thr, BN=64 ----------------
__global__ __launch_bounds__(512) void gemm_proj(const bf16* __restrict__ A,
                                                 const bf16* __restrict__ Bt,
                                                 const float* __restrict__ bias,
                                                 float* __restrict__ C,
                                                 int M, int N, int K) {
  constexpr int BN = 64, WN = 2, MR = 32, MT = 2;
  __shared__ bf16 As0[128 * 32], As1[128 * 32];
  __shared__ bf16 Bs0[BN * 32],  Bs1[BN * 32];
  const int tid = threadIdx.x;
  const int w = tid >> 6, l = tid & 63;
  const int nx = gridDim.x;
  const int nwg = nx * gridDim.y;
  const int flat = blockIdx.y * nx + blockIdx.x;
  const int swz = (flat & 7) * (nwg >> 3) + (flat >> 3);
  const int m0 = (swz / nx) * 128, n0 = (swz % nx) * BN;
  const int wm = w / WN, wn = w % WN;
  const int fr = l & 15, fg = l >> 4;
  const int grow = tid >> 2;
  const int gcol = (tid & 3) * 8;

  f32x4 acc[MT][2] = {};

  for (int k0 = 0; k0 < K; k0 += 64) {
    __syncthreads();
    gload16(A + (size_t)(m0 + grow) * K + k0 + gcol,      As0 + 512 * w);
    gload16(A + (size_t)(m0 + grow) * K + k0 + 32 + gcol, As1 + 512 * w);
    if (w < 4) {
      gload16(Bt + (size_t)(n0 + grow) * K + k0 + gcol,      Bs0 + 512 * w);
      gload16(Bt + (size_t)(n0 + grow) * K + k0 + 32 + gcol, Bs1 + 512 * w);
    }
    __syncthreads();

    bf16x8 af[MT][2], bfv[2][2];
    for (int mt = 0; mt < MT; ++mt) {
      af[mt][0] = *(const bf16x8*)(As0 + (wm * MR + mt * 16 + fr) * 32 + 8 * fg);
      af[mt][1] = *(const bf16x8*)(As1 + (wm * MR + mt * 16 + fr) * 32 + 8 * fg);
    }
    for (int nt = 0; nt < 2; ++nt) {
      bfv[nt][0] = *(const bf16x8*)(Bs0 + (wn * 32 + nt * 16 + fr) * 32 + 8 * fg);
      bfv[nt][1] = *(const bf16x8*)(Bs1 + (wn * 32 + nt * 16 + fr) * 32 + 8 * fg);
    }
    for (int mt = 0; mt < MT; ++mt)
      for (int nt = 0; nt < 2; ++nt) {
        acc[mt][nt] = __builtin_amdgcn_mfma_f32_16x16x32_bf16(af[mt][0], bfv[nt][0], acc[mt][nt], 0, 0, 0);
        acc[mt][nt] = __builtin_amdgcn_mfma_f32_16x16x32_bf16(af[mt][1], bfv[nt][1], acc[mt][nt], 0, 0, 0);
      }
  }

  for (int mt = 0; mt < MT; ++mt)
    for (int nt = 0; nt < 2; ++nt) {
      const int row0 = m0 + wm * MR + mt * 16 + 4 * fg;
      const int col = n0 + wn * 32 + nt * 16 + fr;
      const float bv = bias[col];
      for (int r = 0; r < 4; ++r)
        C[(size_t)(row0 + r) * N + col] = acc[mt][nt][r] + bv;
    }
}

// ---------------- flash attention: 4-wave 64-row q-tile/block, heavy-first, NO setprio ----------------
__global__ __launch_bounds__(256, 3) void attn_k(const bf16* __restrict__ Qw,
                                                 const bf16* __restrict__ Kw,
                                                 const bf16* __restrict__ VtG,
                                                 bf16* __restrict__ AO) {
  __shared__ bf16 Ks[128 * 72];        // 18432 B
  __shared__ bf16 Vt[64 * 136];        // 17408 B
  __shared__ bf16 Ps[4 * 16 * 72];     //  9216 B
  const int tid = threadIdx.x, w = tid >> 6, l = tid & 63;
  const int bid = blockIdx.x;
  const int bh = ((bid & 7) << 2) | ((bid >> 3) & 3);
  const int qt = 31 - (bid >> 5);             // heavy-first
  const int q0 = qt * 64;
  const int fr = l & 15, fg = l >> 4;
  const size_t base = (size_t)bh * 2048 * 64;
  const int qw0 = q0 + w * 16;
  const int q = qw0 + fr;
  bf16* Pw = Ps + w * 16 * 72;
  const int r8 = tid >> 3, c8 = (tid & 7) * 8;
  const int r16 = tid >> 4, c16 = (tid & 15) * 8;

  bf16x8 qf[2];
  for (int t = 0; t < 2; ++t)
    qf[t] = *(const bf16x8*)(Qw + base + (size_t)(qw0 + fr) * 64 + 32 * t + 8 * fg);

  f32x4 oacc[4] = {};
  float lsum = 0.f;
  bf16x8 kreg[4], vreg[4];

  auto load_tile = [&](int kt) {
    for (int c = 0; c < 4; ++c) {
      kreg[c] = *(const bf16x8*)(Kw + base + (size_t)(kt + r8 + 32 * c) * 64 + c8);
      vreg[c] = *(const bf16x8*)(VtG + base + (size_t)(r16 + 16 * c) * 2048 + kt + c16);
    }
  };
  auto write_tile = [&]() {
    for (int c = 0; c < 4; ++c) {
      *(bf16x8*)(Ks + (r8 + 32 * c) * 72 + c8) = kreg[c];
      *(bf16x8*)(Vt + (r16 + 16 * c) * 136 + c16) = vreg[c];
    }
  };

  load_tile(0);
  write_tile();
  __syncthreads();

  for (int kt = 0; kt <= q0; kt += 128) {
    const bool havenext = (kt + 128 <= q0);
    if (havenext) load_tile(kt + 128);      // T14: issue early

    for (int h = 0; h < 2; ++h) {
      const int kh = kt + 64 * h;
      if (kh > q0) break;

      f32x4 sc[4];
      for (int c = 0; c < 4; ++c) {
        bf16x8 kf0 = *(const bf16x8*)(Ks + (64 * h + c * 16 + fr) * 72 + 8 * fg);
        bf16x8 kf1 = *(const bf16x8*)(Ks + (64 * h + c * 16 + fr) * 72 + 32 + 8 * fg);
        f32x4 z = {};
        z = __builtin_amdgcn_mfma_f32_16x16x32_bf16(kf0, qf[0], z, 0, 0, 0);
        sc[c] = __builtin_amdgcn_mfma_f32_16x16x32_bf16(kf1, qf[1], z, 0, 0, 0);
      }

      const bool need_mask = (kh + 63 > qw0);
      float psum = 0.f;
      for (int c = 0; c < 4; ++c) {
        bf16x4 pb;
        for (int r = 0; r < 4; ++r) {
          float s = sc[c][r];
          if (need_mask && (kh + c * 16 + 4 * fg + r > q)) s = MNEG;
          const float pv = __builtin_amdgcn_exp2f(s);
          psum += pv;
          pb[r] = (bf16)pv;
        }
        *(bf16x4*)(Pw + fr * 72 + c * 16 + 4 * fg) = pb;
      }
      psum += __shfl_xor(psum, 16, 64);
      psum += __shfl_xor(psum, 32, 64);
      lsum += psum;

      asm volatile("" ::: "memory");   // P writes before P reads (in-wave DS order)
      for (int t = 0; t < 2; ++t) {
        bf16x8 pa = *(const bf16x8*)(Pw + fr * 72 + 32 * t + 8 * fg);
        for (int dt = 0; dt < 4; ++dt) {
          bf16x8 vf = *(const bf16x8*)(Vt + (dt * 16 + fr) * 136 + 64 * h + 32 * t + 8 * fg);
          oacc[dt] = __builtin_amdgcn_mfma_f32_16x16x32_bf16(pa, vf, oacc[dt], 0, 0, 0);
        }
      }
      asm volatile("" ::: "memory");   // Pw reused next half
    }

    if (!havenext) break;
    __syncthreads();
    write_tile();                           // T14: write-late
    __syncthreads();
  }

  const int b = bh >> 4, h = bh & 15;
  float linv[4];
  for (int r = 0; r < 4; ++r)
    linv[r] = 1.f / __shfl(lsum, (l & 48) | (4 * fg + r), 64);
  for (int dt = 0; dt < 4; ++dt)
    for (int r = 0; r < 4; ++r) {
      const int qq = qw0 + 4 * fg + r;
      AO[(size_t)(b * 2048 + qq) * 1024 + h * 64 + dt * 16 + fr] =
          (bf16)(oacc[dt][r] * linv[r]);
    }
}

// ---------------- launch ----------------
extern "C" void kernel_launch(void* const* d_in, const int* in_sizes, int n_in,
                              void* d_out, int out_size, void* d_ws, size_t ws_size,
                              hipStream_t stream) {
  const float* x      = (const float*)d_in[0];
  const float* W_attn = (const float*)d_in[1];
  const float* b_attn = (const float*)d_in[2];
  const float* W_proj = (const float*)d_in[3];
  const float* b_proj = (const float*)d_in[4];
  float* out = (float*)d_out;

  char* ws = (char*)d_ws;
  bf16* WaT = (bf16*)(ws);                 // 6291456 B
  bf16* WpT = (bf16*)(ws + 6291456);       // 2097152 B
  bf16* Qw  = (bf16*)(ws + 8388608);       // [B,H,S,D] (pre-scaled by QSCALE)
  bf16* Kw  = (bf16*)(ws + 16777216);      // [B,H,S,D]
  bf16* VtG = (bf16*)(ws + 25165824);      // [B,H,D,S]
  bf16* AO  = (bf16*)(ws + 33554432);      // [B,S,E] bf16; aliased as xb pre-attn
  bf16* xb  = AO;

  prep_k<<<3072, 256, 0, stream>>>(x, xb, W_attn, WaT, W_proj, WpT);

  gemm_qkv<<<dim3(24, 32), 512, 0, stream>>>(
      xb, WaT, b_attn, Qw, Kw, VtG, 4096, 3072, 1024);

  attn_k<<<1024, 256, 0, stream>>>(Qw, Kw, VtG, AO);

  gemm_proj<<<dim3(16, 32), 512, 0, stream>>>(
      AO, WpT, b_proj, out, 4096, 1024, 1024);
}